// Round 3
// baseline (561.544 us; speedup 1.0000x reference)
//
#include <hip/hip_runtime.h>

#define IMG_H 512
#define IMG_W 512
#define TILE_H 32
#define ROWS (TILE_H + 10)   // 42 staged rows per wave-tile

__device__ __forceinline__ int reflect512(int t) {
    t = (t < 0) ? -t : t;
    t = (t > 511) ? 1022 - t : t;
    return t;
}

// 128-thread blocks = 2 INDEPENDENT waves (own LDS half, own 64x32 tile, no
// barriers). Per wave: 3-deep global->register prefetch pipeline feeds a
// double-buffered LDS row; cross-lane ds_reads are ordered against the
// ds_writes by an explicit lgkmcnt(0)+sched_barrier fence ("memory" clobber
// gives IR/MIR ordering; lgkmcnt(0) gives HW completion; vmcnt untouched so
// the prefetch stays in flight). Horizontal 11-tap blur of {a,b,a^2+b^2,ab}
// from LDS; vertical 11-tap blur from a 12-deep register ring (static
// indices under unroll-12); fused SSIM epilogue. fp32 -> pure VALU kernel.
__global__ __launch_bounds__(128, 6) void ssim_kernel(
    const float* __restrict__ img1,
    const float* __restrict__ img2,
    float* __restrict__ out)
{
    // gaussian(11, sigma=1.5), L1-normalized (symmetric)
    const float kW[11] = {
        0.00102838f, 0.00759876f, 0.03600078f, 0.10936055f, 0.21300561f,
        0.26601182f, 0.21300561f, 0.10936055f, 0.03600078f, 0.00759876f,
        0.00102838f };
    const float C1 = 0.0001f;  // (0.01*1)^2
    const float C2 = 0.0009f;  // (0.03*1)^2

    const int tid  = threadIdx.x;
    const int wv   = tid >> 6;        // wave id within block (0/1)
    const int lane = tid & 63;
    const int x0 = blockIdx.x * 64;
    const int y0 = blockIdx.y * 64 + wv * TILE_H;
    const size_t pbase = (size_t)blockIdx.z * (IMG_H * IMG_W);
    const float* __restrict__ p1 = img1 + pbase;
    const float* __restrict__ p2 = img2 + pbase;
    float* __restrict__ po = out + pbase;

    __shared__ float2 buf[2][2][80];   // [wave][parity][slot], 74 used
    float2 (* const bufw)[80] = buf[wv];

    // 12-deep register rings for the 4 horizontally-blurred quantities
    float ring1[12], ring2[12], ringSS[12], ringAB[12];
    // 3-deep prefetch registers (main + tail, both images)
    float pfa[3], pfb[3], pfat[3], pfbt[3];

    const int xo  = x0 + lane;
    const int gx0 = reflect512(x0 - 5 + lane);        // all 64 lanes
    const int gx1 = reflect512(x0 - 5 + lane + 64);   // lanes 0..9 only

    // ---- prologue: issue loads for rows 0,1,2 ----
    #pragma unroll
    for (int p = 0; p < 3; ++p) {
        const int gy = reflect512(y0 - 5 + p);
        const float* r1p = p1 + (size_t)gy * IMG_W;
        const float* r2p = p2 + (size_t)gy * IMG_W;
        pfa[p] = r1p[gx0];
        pfb[p] = r2p[gx0];
        if (lane < 10) { pfat[p] = r1p[gx1]; pfbt[p] = r2p[gx1]; }
    }

    for (int so = 0; so < 48; so += 12) {
        #pragma unroll
        for (int r = 0; r < 12; ++r) {
            const int s = so + r;            // uniform row step
            if (s < ROWS) {
                const int pi  = r % 3;       // static: so % 3 == 0
                const int par = r & 1;       // static: so even
                float2* b = bufw[par];

                // ---- commit prefetched row s to LDS ----
                b[lane] = make_float2(pfa[pi], pfb[pi]);
                if (lane < 10)
                    b[lane + 64] = make_float2(pfat[pi], pfbt[pi]);

                // ---- issue prefetch for row s+3 into the freed slot ----
                if (s + 3 < ROWS) {
                    const int gy = reflect512(y0 - 5 + s + 3);
                    const float* r1p = p1 + (size_t)gy * IMG_W;
                    const float* r2p = p2 + (size_t)gy * IMG_W;
                    pfa[pi] = r1p[gx0];
                    pfb[pi] = r2p[gx0];
                    if (lane < 10) { pfat[pi] = r1p[gx1]; pfbt[pi] = r2p[gx1]; }
                }

                // ---- ORDERING FENCE: cross-lane RAW on LDS ----
                // ds_write above / ds_read below touch different per-lane
                // addresses, so LLVM would otherwise reorder them (rule-18
                // class hazard). lgkmcnt(0) waits only the 2 ds_writes;
                // vmcnt (prefetch) stays in flight.
                asm volatile("s_waitcnt lgkmcnt(0)" ::: "memory");
                __builtin_amdgcn_sched_barrier(0);

                // ---- horizontal 11-tap blur of {a, b, a^2+b^2, ab} ----
                float h1 = 0.f, h2 = 0.f, hss = 0.f, hab = 0.f;
                #pragma unroll
                for (int k = 0; k < 11; ++k) {
                    const float2 t = b[lane + k];
                    const float wk = kW[k];
                    const float ta = wk * t.x;
                    const float tb = wk * t.y;
                    h1 += ta;
                    h2 += tb;
                    hss = fmaf(ta, t.x, hss);
                    hss = fmaf(tb, t.y, hss);
                    hab = fmaf(ta, t.y, hab);
                }
                ring1[r] = h1; ring2[r] = h2; ringSS[r] = hss; ringAB[r] = hab;

                // ---- vertical 11-tap blur + SSIM epilogue ----
                if (s >= 10) {
                    float v1 = 0.f, v2 = 0.f, vss = 0.f, vab = 0.f;
                    #pragma unroll
                    for (int d = 0; d < 11; ++d) {
                        const int slot = (r - d + 12) % 12;  // static
                        const float wd = kW[d];              // symmetric
                        v1  = fmaf(wd, ring1[slot],  v1);
                        v2  = fmaf(wd, ring2[slot],  v2);
                        vss = fmaf(wd, ringSS[slot], vss);
                        vab = fmaf(wd, ringAB[slot], vab);
                    }
                    const float mu12 = v1 * v2;
                    const float musq = fmaf(v1, v1, v2 * v2);
                    const float sgsum = vss - musq;          // sig1^2+sig2^2
                    const float sg12  = vab - mu12;          // sigma12
                    const float num = fmaf(2.f, mu12, C1) * fmaf(2.f, sg12, C2);
                    const float den = (musq + C1) * (sgsum + C2);
                    float rden = __builtin_amdgcn_rcpf(den);
                    rden = rden * (2.f - den * rden);        // 1 Newton step
                    const float ssim = num * rden;
                    const float loss = 0.5f * fminf(fmaxf(1.f - ssim, 0.f), 1.f);
                    po[(size_t)(y0 + s - 10) * IMG_W + xo] = loss;
                }
            }
        }
    }
}

extern "C" void kernel_launch(void* const* d_in, const int* in_sizes, int n_in,
                              void* d_out, int out_size, void* d_ws, size_t ws_size,
                              hipStream_t stream) {
    const float* img1 = (const float*)d_in[0];
    const float* img2 = (const float*)d_in[1];
    float* out = (float*)d_out;
    // 8 x 8 x 48 blocks of 128 threads; each block = 2 independent waves,
    // each wave one 64x32 tile -> 6144 wave-tiles, 24 waves/CU.
    dim3 grid(IMG_W / 64, IMG_H / 64, 48);
    ssim_kernel<<<grid, dim3(128, 1, 1), 0, stream>>>(img1, img2, out);
}

// Round 4
// 202.179 us; speedup vs baseline: 2.7775x; 2.7775x over previous
//
#include <hip/hip_runtime.h>

#define IMG_H 512
#define IMG_W 512
#define TILE_H 32
#define ROWS (TILE_H + 10)   // 42 staged rows per wave-tile

__device__ __forceinline__ int reflect512(int t) {
    t = (t < 0) ? -t : t;
    t = (t > 511) ? 1022 - t : t;
    return t;
}

// 128-thread blocks = 2 INDEPENDENT waves (own LDS half, own 64x32 tile, no
// barriers). Per wave: 2-deep global->register prefetch pipeline feeds a
// double-buffered LDS row; cross-lane ds_reads are ordered against the
// ds_writes by lgkmcnt(0)+sched_barrier ("memory" clobber = IR ordering,
// lgkmcnt(0) = HW completion; vmcnt untouched so prefetch stays in flight).
// Horizontal 11-tap blur of {a,b,a^2+b^2,ab} from LDS; vertical 11-tap blur
// from an 11-deep register ring. The 42-step row loop is FULLY UNROLLED so
// every ring/parity index is compile-time (no scratch, rule #20).
// NOTE: no min-waves in launch_bounds — R3's (128,6) forced VGPR=40 and
// spilled ~1.6 GB of scratch traffic (FETCH 1.1GB). Unconstrained alloc
// lands ~60 VGPR -> 8 waves/SIMD bin.
__global__ __launch_bounds__(128) void ssim_kernel(
    const float* __restrict__ img1,
    const float* __restrict__ img2,
    float* __restrict__ out)
{
    // gaussian(11, sigma=1.5), L1-normalized (symmetric)
    const float kW[11] = {
        0.00102838f, 0.00759876f, 0.03600078f, 0.10936055f, 0.21300561f,
        0.26601182f, 0.21300561f, 0.10936055f, 0.03600078f, 0.00759876f,
        0.00102838f };
    const float C1 = 0.0001f;  // (0.01*1)^2
    const float C2 = 0.0009f;  // (0.03*1)^2

    const int tid  = threadIdx.x;
    const int wv   = tid >> 6;        // wave id within block (0/1)
    const int lane = tid & 63;
    const int x0 = blockIdx.x * 64;
    const int y0 = blockIdx.y * 64 + wv * TILE_H;
    const size_t pbase = (size_t)blockIdx.z * (IMG_H * IMG_W);
    const float* __restrict__ p1 = img1 + pbase;
    const float* __restrict__ p2 = img2 + pbase;
    float* __restrict__ po = out + pbase;

    __shared__ float2 buf[2][2][80];   // [wave][parity][slot], 74 used
    float2 (* const bufw)[80] = buf[wv];

    // 11-deep register rings for the 4 horizontally-blurred quantities
    float ring1[11], ring2[11], ringSS[11], ringAB[11];
    // 2-deep prefetch registers (main + tail, both images)
    float pfa[2], pfb[2], pfat[2], pfbt[2];

    const int xo  = x0 + lane;
    const int gx0 = reflect512(x0 - 5 + lane);        // all 64 lanes
    const int gx1 = reflect512(x0 - 5 + lane + 64);   // lanes 0..9 only

    // ---- prologue: issue loads for rows 0,1 ----
    #pragma unroll
    for (int p = 0; p < 2; ++p) {
        const int gy = reflect512(y0 - 5 + p);
        const float* r1p = p1 + (size_t)gy * IMG_W;
        const float* r2p = p2 + (size_t)gy * IMG_W;
        pfa[p] = r1p[gx0];
        pfb[p] = r2p[gx0];
        if (lane < 10) { pfat[p] = r1p[gx1]; pfbt[p] = r2p[gx1]; }
    }

    #pragma unroll
    for (int s = 0; s < ROWS; ++s) {   // fully unrolled: s compile-time
        const int pi = s & 1;          // prefetch slot == LDS parity
        float2* b = bufw[pi];

        // ---- commit prefetched row s to LDS ----
        b[lane] = make_float2(pfa[pi], pfb[pi]);
        if (lane < 10)
            b[lane + 64] = make_float2(pfat[pi], pfbt[pi]);

        // ---- issue prefetch for row s+2 into the freed slot ----
        if (s + 2 < ROWS) {
            const int gy = reflect512(y0 - 5 + s + 2);
            const float* r1p = p1 + (size_t)gy * IMG_W;
            const float* r2p = p2 + (size_t)gy * IMG_W;
            pfa[pi] = r1p[gx0];
            pfb[pi] = r2p[gx0];
            if (lane < 10) { pfat[pi] = r1p[gx1]; pfbt[pi] = r2p[gx1]; }
        }

        // ---- ORDERING FENCE for the cross-lane LDS RAW ----
        // (compiler would otherwise reorder per-lane "non-aliasing"
        // ds_reads above the ds_writes). lgkmcnt(0) waits only DS ops;
        // the global prefetch (vmcnt) stays in flight.
        asm volatile("s_waitcnt lgkmcnt(0)" ::: "memory");
        __builtin_amdgcn_sched_barrier(0);

        // ---- horizontal 11-tap blur of {a, b, a^2+b^2, ab} ----
        float h1 = 0.f, h2 = 0.f, hss = 0.f, hab = 0.f;
        #pragma unroll
        for (int k = 0; k < 11; ++k) {
            const float2 t = b[lane + k];
            const float wk = kW[k];
            const float ta = wk * t.x;
            const float tb = wk * t.y;
            h1 += ta;
            h2 += tb;
            hss = fmaf(ta, t.x, hss);
            hss = fmaf(tb, t.y, hss);
            hab = fmaf(ta, t.y, hab);
        }
        const int wr = s % 11;         // compile-time
        ring1[wr] = h1; ring2[wr] = h2; ringSS[wr] = hss; ringAB[wr] = hab;

        // ---- vertical 11-tap blur + SSIM epilogue ----
        if (s >= 10) {
            float v1 = 0.f, v2 = 0.f, vss = 0.f, vab = 0.f;
            #pragma unroll
            for (int d = 0; d < 11; ++d) {
                const int slot = (s - d) % 11;   // compile-time
                const float wd = kW[d];          // symmetric kernel
                v1  = fmaf(wd, ring1[slot],  v1);
                v2  = fmaf(wd, ring2[slot],  v2);
                vss = fmaf(wd, ringSS[slot], vss);
                vab = fmaf(wd, ringAB[slot], vab);
            }
            const float mu12 = v1 * v2;
            const float musq = fmaf(v1, v1, v2 * v2);
            const float sgsum = vss - musq;          // sig1^2 + sig2^2
            const float sg12  = vab - mu12;          // sigma12
            const float num = fmaf(2.f, mu12, C1) * fmaf(2.f, sg12, C2);
            const float den = (musq + C1) * (sgsum + C2);
            float rden = __builtin_amdgcn_rcpf(den);
            rden = rden * (2.f - den * rden);        // 1 Newton step
            const float ssim = num * rden;
            const float loss = 0.5f * fminf(fmaxf(1.f - ssim, 0.f), 1.f);
            po[(size_t)(y0 + s - 10) * IMG_W + xo] = loss;
        }
    }
}

extern "C" void kernel_launch(void* const* d_in, const int* in_sizes, int n_in,
                              void* d_out, int out_size, void* d_ws, size_t ws_size,
                              hipStream_t stream) {
    const float* img1 = (const float*)d_in[0];
    const float* img2 = (const float*)d_in[1];
    float* out = (float*)d_out;
    // 8 x 8 x 48 blocks of 128 threads; each block = 2 independent waves,
    // each wave one 64x32 tile -> 6144 wave-tiles, 24 waves/CU.
    dim3 grid(IMG_W / 64, IMG_H / 64, 48);
    ssim_kernel<<<grid, dim3(128, 1, 1), 0, stream>>>(img1, img2, out);
}